// Round 12
// baseline (10.271 us; speedup 1.0000x reference)
//
#include <hip/hip_runtime.h>

#define N_QUERIES 2097152

typedef float fx4 __attribute__((ext_vector_type(4)));

// Per query: 2x b128 position-pair gathers + 1x b128 color gather.
__device__ __forceinline__ fx4 nearest_col(float qx, float qy,
                                           const fx4* pr, const fx4* cl)
{
    // nearest 2x2 cell-center block; jitter margin (0.1179 vs 0.0955) proves
    // the global argmin over all 64 jittered sites lies in this block.
    float fx = qx * 8.0f - 0.5f;
    float fy = qy * 8.0f - 0.5f;
    float fi = fminf(fmaxf(floorf(fx), 0.0f), 6.0f);
    float fj = fminf(fmaxf(floorf(fy), 0.0f), 6.0f);
    int k0 = (int)fi * 8 + (int)fj;

    fx4 r0 = pr[k0];       // {px[k0],py[k0],px[k0+1],py[k0+1]}
    fx4 r1 = pr[k0 + 8];   // {px[k0+8],py[k0+8],px[k0+9],py[k0+9]}

    // ascending k + strict '<' == np.argmin tie-break;
    // __fmul_rn/__fadd_rn match numpy's separate roundings (no FMA).
    float dx, dy, d2, best;
    int bk = k0;
    dx = qx - r0.x; dy = qy - r0.y;
    best = __fadd_rn(__fmul_rn(dx, dx), __fmul_rn(dy, dy));
    dx = qx - r0.z; dy = qy - r0.w;
    d2 = __fadd_rn(__fmul_rn(dx, dx), __fmul_rn(dy, dy));
    if (d2 < best) { best = d2; bk = k0 + 1; }
    dx = qx - r1.x; dy = qy - r1.y;
    d2 = __fadd_rn(__fmul_rn(dx, dx), __fmul_rn(dy, dy));
    if (d2 < best) { best = d2; bk = k0 + 8; }
    dx = qx - r1.z; dy = qy - r1.w;
    d2 = __fadd_rn(__fmul_rn(dx, dx), __fmul_rn(dy, dy));
    if (d2 < best) { best = d2; bk = k0 + 9; }

    return cl[bk];
}

// 128-thread (2-wave) blocks, 8192 blocks, ZERO barriers: each wave builds a
// private table copy (lane L builds site L; L2-hot) while its x-load is in
// flight, then computes/stages/stores independently. Finest retire-unit
// granularity at full 32 waves/CU occupancy.
__global__ __launch_bounds__(128) void voronoi_kernel(
    const float* __restrict__ x,
    const float* __restrict__ p,
    float* __restrict__ out)
{
    __shared__ fx4 pairs[2][64];   // per-wave private site tables
    __shared__ fx4 cols [2][64];
    __shared__ fx4 oc   [2][96];   // per-wave output staging (128 q x 3 floats)

    const int tid  = threadIdx.x;
    const int wid  = tid >> 6;
    const int lane = tid & 63;

    // unit-stride x load issued FIRST; stays in flight through table build
    // (the lgkmcnt fence below does not wait on vmcnt)
    const fx4* __restrict__ x4 =
        (const fx4*)x + (size_t)blockIdx.x * 128 + 64 * wid;
    fx4 a = x4[lane];   // queries 256b+128w+2L, +1

    // per-wave table build: lane L builds site L (p is tiny, L2-hot)
    {
        const float* ps = p + lane * 5;
        int nb = ((lane & 7) == 7) ? lane : lane + 1;  // col+1 neighbor (col=7 never read)
        const float* pn = p + nb * 5;
        pairs[wid][lane] = fx4{ps[0], ps[1], pn[0], pn[1]};
        cols [wid][lane] = fx4{ps[2], ps[3], ps[4], 0.0f};
    }
    // cross-lane same-wave LDS RAW: DS pipe is in-order per wave (validated
    // R9/R11); fence compiler + wait LDS writes
    asm volatile("s_waitcnt lgkmcnt(0)" ::: "memory");
    __builtin_amdgcn_sched_barrier(0);

    fx4 c0 = nearest_col(a.x, a.y, pairs[wid], cols[wid]);
    fx4 c1 = nearest_col(a.z, a.w, pairs[wid], cols[wid]);

    // stage: lane L -> wave-rel floats [6L, 6L+6)
    float* o = (float*)&oc[wid][0] + 6 * lane;
    o[0] = c0.x; o[1] = c0.y; o[2] = c0.z;
    o[3] = c1.x; o[4] = c1.y; o[5] = c1.z;

    asm volatile("s_waitcnt lgkmcnt(0)" ::: "memory");
    __builtin_amdgcn_sched_barrier(0);

    // readback unit-stride, nontemporal store: 96 fx4 per wave
    const fx4* ocv = oc[wid];
    fx4* __restrict__ o4 = (fx4*)out + (size_t)blockIdx.x * 192 + 96 * wid;
    __builtin_nontemporal_store(ocv[lane], &o4[lane]);
    if (lane < 32)
        __builtin_nontemporal_store(ocv[64 + lane], &o4[64 + lane]);
}

extern "C" void kernel_launch(void* const* d_in, const int* in_sizes, int n_in,
                              void* d_out, int out_size, void* d_ws, size_t ws_size,
                              hipStream_t stream) {
    const float* x = (const float*)d_in[0];
    const float* p = (const float*)d_in[1];
    float* out = (float*)d_out;

    const int block = 128;
    const int grid = N_QUERIES / 256;   // 8192 blocks, 2-wave retire units
    voronoi_kernel<<<grid, block, 0, stream>>>(x, p, out);
}

// Round 13
// 10.091 us; speedup vs baseline: 1.0178x; 1.0178x over previous
//
#include <hip/hip_runtime.h>

#define N_QUERIES 2097152

typedef float fx4 __attribute__((ext_vector_type(4)));

// Per query: 2x b128 position-pair gathers + 1x b128 color gather.
__device__ __forceinline__ fx4 nearest_col(float qx, float qy,
                                           const fx4* pr, const fx4* cl)
{
    // nearest 2x2 cell-center block; jitter margin (0.1179 vs 0.0955) proves
    // the global argmin over all 64 jittered sites lies in this block.
    float fx = qx * 8.0f - 0.5f;
    float fy = qy * 8.0f - 0.5f;
    float fi = fminf(fmaxf(floorf(fx), 0.0f), 6.0f);
    float fj = fminf(fmaxf(floorf(fy), 0.0f), 6.0f);
    int k0 = (int)fi * 8 + (int)fj;

    fx4 r0 = pr[k0];       // {px[k0],py[k0],px[k0+1],py[k0+1]}
    fx4 r1 = pr[k0 + 8];   // {px[k0+8],py[k0+8],px[k0+9],py[k0+9]}

    // ascending k + strict '<' == np.argmin tie-break;
    // __fmul_rn/__fadd_rn match numpy's separate roundings (no FMA).
    float dx, dy, d2, best;
    int bk = k0;
    dx = qx - r0.x; dy = qy - r0.y;
    best = __fadd_rn(__fmul_rn(dx, dx), __fmul_rn(dy, dy));
    dx = qx - r0.z; dy = qy - r0.w;
    d2 = __fadd_rn(__fmul_rn(dx, dx), __fmul_rn(dy, dy));
    if (d2 < best) { best = d2; bk = k0 + 1; }
    dx = qx - r1.x; dy = qy - r1.y;
    d2 = __fadd_rn(__fmul_rn(dx, dx), __fmul_rn(dy, dy));
    if (d2 < best) { best = d2; bk = k0 + 8; }
    dx = qx - r1.z; dy = qy - r1.w;
    d2 = __fadd_rn(__fmul_rn(dx, dx), __fmul_rn(dy, dy));
    if (d2 < best) { best = d2; bk = k0 + 9; }

    return cl[bk];
}

// 128-thread (2-wave) blocks, 256 queries each, 8192 blocks. Small blocks
// retire at 2-wave granularity, so fresh blocks (load phase) launch while
// older blocks drain stores -> read/write streams interleave in steady state
// instead of the one-generation burst serialization of 1024-query blocks.
__global__ __launch_bounds__(128) void voronoi_kernel(
    const float* __restrict__ x,
    const float* __restrict__ p,
    float* __restrict__ out)
{
    __shared__ fx4 pairs[64];    // shared site tables (read-only after build)
    __shared__ fx4 cols [64];
    __shared__ fx4 oc[2][96];    // per-wave output staging (128 q x 3 floats)

    const int tid  = threadIdx.x;
    const int wid  = tid >> 6;
    const int lane = tid & 63;

    // unit-stride load: lane L of wave w -> queries 2L,2L+1 of wave's 128
    const fx4* __restrict__ x4 =
        (const fx4*)x + (size_t)blockIdx.x * 128 + 64 * wid;
    fx4 a = x4[lane];

    if (tid < 64) {
        const float* ps = p + tid * 5;
        int nb = ((tid & 7) == 7) ? tid : tid + 1;   // col+1 neighbor (col=7 never read)
        const float* pn = p + nb * 5;
        pairs[tid] = fx4{ps[0], ps[1], pn[0], pn[1]};
        cols [tid] = fx4{ps[2], ps[3], ps[4], 0.0f};
    }
    __syncthreads();   // tables ready; waves decouple after this

    fx4 c0 = nearest_col(a.x, a.y, pairs, cols);
    fx4 c1 = nearest_col(a.z, a.w, pairs, cols);

    // stage: lane L -> wave-rel floats [6L, 6L+6)
    float* o = (float*)&oc[wid][0] + 6 * lane;
    o[0] = c0.x; o[1] = c0.y; o[2] = c0.z;
    o[3] = c1.x; o[4] = c1.y; o[5] = c1.z;

    // within-wave LDS RAW: HW DS pipe is in-order per wave; fence the compiler
    asm volatile("s_waitcnt lgkmcnt(0)" ::: "memory");
    __builtin_amdgcn_sched_barrier(0);

    // readback unit-stride, nontemporal store: 96 fx4 per wave
    const fx4* ocv = oc[wid];
    fx4* __restrict__ o4 = (fx4*)out + (size_t)blockIdx.x * 192 + 96 * wid;
    __builtin_nontemporal_store(ocv[lane], &o4[lane]);
    if (lane < 32)
        __builtin_nontemporal_store(ocv[64 + lane], &o4[64 + lane]);
}

extern "C" void kernel_launch(void* const* d_in, const int* in_sizes, int n_in,
                              void* d_out, int out_size, void* d_ws, size_t ws_size,
                              hipStream_t stream) {
    const float* x = (const float*)d_in[0];
    const float* p = (const float*)d_in[1];
    float* out = (float*)d_out;

    const int block = 128;
    const int grid = N_QUERIES / 256;   // 8192 blocks, 2-wave retire units
    voronoi_kernel<<<grid, block, 0, stream>>>(x, p, out);
}